// Round 5
// baseline (463.296 us; speedup 1.0000x reference)
//
#include <hip/hip_runtime.h>
#include <math.h>

// Problem: bs=8, seq=2048, d_in=d_out=2048, R=8, ctr_out=32, ctr_final=4
// ws layout (floats): A[8*8*2048] | B[8*8*2048]  (B has SCALING folded in)

#define BS 8
#define SEQ 2048
#define DIM 2048
#define RR 8
#define SCALING 2.0f   // 16.0 / R

typedef float vf4 __attribute__((ext_vector_type(4)));

// ---------------------------------------------------------------------------
// Kernel 1: gating MLP + A/B generation. (unchanged — ~6 µs, off critical path)
// ---------------------------------------------------------------------------
__global__ void gate_ab_kernel(const float* __restrict__ ctr,
                               const float* __restrict__ gamma,
                               const float* __restrict__ beta,
                               const float* __restrict__ W1,
                               const float* __restrict__ b1,
                               const float* __restrict__ W2,
                               const float* __restrict__ b2,
                               const float* __restrict__ Wa,
                               const float* __restrict__ Wb,
                               float* __restrict__ A,
                               float* __restrict__ B) {
    __shared__ float z_s[BS][32];
    __shared__ float h_s[BS][60];
    __shared__ float logit_s[BS][4];
    __shared__ float gate_s[BS][4];
    const int tid = threadIdx.x;

    {
        const int b = tid >> 5, i = tid & 31;
        float v = ctr[b * 32 + i];
        float s = v;
        #pragma unroll
        for (int m = 16; m; m >>= 1) s += __shfl_xor(s, m, 64);
        const float mu = s * (1.0f / 32.0f);
        const float d = v - mu;
        float sq = d * d;
        #pragma unroll
        for (int m = 16; m; m >>= 1) sq += __shfl_xor(sq, m, 64);
        const float var = sq * (1.0f / 32.0f);
        z_s[b][i] = d * rsqrtf(var + 1e-5f) * gamma[i] + beta[i];
    }
    __syncthreads();

    for (int idx = tid; idx < BS * 60; idx += 256) {
        const int b = idx / 60, j = idx % 60;
        float acc = b1[j];
        #pragma unroll
        for (int k = 0; k < 32; ++k) acc += z_s[b][k] * W1[j * 32 + k];
        h_s[b][j] = fmaxf(acc, 0.0f);
    }
    __syncthreads();

    if (tid < 32) {
        const int b = tid >> 2, c = tid & 3;
        float acc = b2[c];
        for (int k = 0; k < 60; ++k) acc += h_s[b][k] * W2[c * 60 + k];
        logit_s[b][c] = acc;
    }
    __syncthreads();

    if (tid < 8) {
        float m = logit_s[tid][0];
        #pragma unroll
        for (int c = 1; c < 4; ++c) m = fmaxf(m, logit_s[tid][c]);
        float e[4], s = 0.0f;
        #pragma unroll
        for (int c = 0; c < 4; ++c) { e[c] = expf(logit_s[tid][c] - m); s += e[c]; }
        const float inv = 1.0f / s;
        #pragma unroll
        for (int c = 0; c < 4; ++c) gate_s[tid][c] = e[c] * inv;
    }
    __syncthreads();

    const vf4* __restrict__ Wa4 = (const vf4*)Wa;
    const vf4* __restrict__ Wb4 = (const vf4*)Wb;
    const int total = BS * RR * DIM;   // 131072
    for (int idx = blockIdx.x * 256 + tid; idx < total; idx += gridDim.x * 256) {
        const int b = idx >> 14, rd = idx & 16383;
        const vf4 g = *(const vf4*)gate_s[b];
        const vf4 wa = Wa4[rd];
        A[idx] = g.x * wa.x + g.y * wa.y + g.z * wa.z + g.w * wa.w;
        const vf4 wb = Wb4[rd];
        B[idx] = SCALING * (g.x * wb.x + g.y * wb.y + g.z * wb.z + g.w * wb.w);
    }
}

// ---------------------------------------------------------------------------
// Fused kernel: NO LDS, NO BARRIERS, plain float4 stores.
// This is the round-1 structure (measured streaming at 2.9 TB/s even while
// RMW-amplified to 858 MB) with the single bug fixed: NT vector stores
// scalarized into 4B/lane partial-line writes -> 4x write amp + RMW fetches
// (WRITE 556 MB, FETCH +148 MB). Plain vf4 stores are full-line and clean
// (v1 measured exactly 133 MB).
// Each wave owns 4 seq rows end-to-end: dot x rows against A (L2-resident),
// butterfly-reduce in-register, multiply into B (L2-resident), store.
// Reads (x from HBM, A/B from L2) and writes mix continuously across waves
// -> full-duplex HBM streaming, no phase alternation, no xa round-trip.
// ---------------------------------------------------------------------------
__global__ void __launch_bounds__(256, 4)
fused_kernel(const float* __restrict__ x, const float* __restrict__ A,
             const float* __restrict__ B, float* __restrict__ out) {
    const int b    = blockIdx.x >> 7;     // 128 blocks per sample
    const int tile = blockIdx.x & 127;    // 16 rows per block
    const int wave = threadIdx.x >> 6, lane = threadIdx.x & 63;

    const float* __restrict__ xr =
        x + ((size_t)(b * SEQ + tile * 16 + wave * 4)) * DIM;
    const float* __restrict__ Ab = A + b * (RR * DIM);

    float acc[4][8];
    #pragma unroll
    for (int i = 0; i < 4; ++i)
        #pragma unroll
        for (int r = 0; r < 8; ++r) acc[i][r] = 0.0f;

    // ---- phase 1: xa = x . A^T, x-loads pipelined 1 deep ----
    vf4 xcur[4], xnxt[4];
    {
        const int d0 = lane * 4;
        #pragma unroll
        for (int i = 0; i < 4; ++i)
            xcur[i] = *(const vf4*)&xr[(size_t)i * DIM + d0];
    }
    #pragma unroll
    for (int j = 0; j < 8; ++j) {
        const int d = j * 256 + lane * 4;
        if (j < 7) {
            #pragma unroll
            for (int i = 0; i < 4; ++i)
                xnxt[i] = *(const vf4*)&xr[(size_t)i * DIM + d + 256];
        }
        vf4 a4[8];
        #pragma unroll
        for (int r = 0; r < 8; ++r) a4[r] = *(const vf4*)&Ab[r * DIM + d];
        #pragma unroll
        for (int i = 0; i < 4; ++i) {
            #pragma unroll
            for (int r = 0; r < 8; ++r)
                acc[i][r] += xcur[i].x * a4[r].x + xcur[i].y * a4[r].y +
                             xcur[i].z * a4[r].z + xcur[i].w * a4[r].w;
        }
        #pragma unroll
        for (int i = 0; i < 4; ++i) xcur[i] = xnxt[i];
    }

    // butterfly reduce across 64 lanes -> every lane holds xa[i][r]
    float xa[4][8];
    #pragma unroll
    for (int i = 0; i < 4; ++i) {
        #pragma unroll
        for (int r = 0; r < 8; ++r) {
            float v = acc[i][r];
            #pragma unroll
            for (int off = 32; off; off >>= 1) v += __shfl_xor(v, off, 64);
            xa[i][r] = v;
        }
    }

    // ---- phase 2: out = xa . B, B from L2, PLAIN float4 stores ----
    const float* __restrict__ Bb = B + b * (RR * DIM);
    float* __restrict__ ob =
        out + ((size_t)(b * SEQ + tile * 16 + wave * 4)) * DIM;
    #pragma unroll
    for (int j = 0; j < 8; ++j) {
        const int o = j * 256 + lane * 4;
        vf4 b4[8];
        #pragma unroll
        for (int r = 0; r < 8; ++r) b4[r] = *(const vf4*)&Bb[r * DIM + o];
        #pragma unroll
        for (int i = 0; i < 4; ++i) {
            vf4 v = {0.0f, 0.0f, 0.0f, 0.0f};
            #pragma unroll
            for (int r = 0; r < 8; ++r) {
                v.x += xa[i][r] * b4[r].x;
                v.y += xa[i][r] * b4[r].y;
                v.z += xa[i][r] * b4[r].z;
                v.w += xa[i][r] * b4[r].w;
            }
            *(vf4*)&ob[(size_t)i * DIM + o] = v;
        }
    }
}

extern "C" void kernel_launch(void* const* d_in, const int* in_sizes, int n_in,
                              void* d_out, int out_size, void* d_ws, size_t ws_size,
                              hipStream_t stream) {
    const float* x     = (const float*)d_in[0];
    const float* ctr   = (const float*)d_in[1];
    const float* gamma = (const float*)d_in[2];
    const float* beta  = (const float*)d_in[3];
    const float* W1    = (const float*)d_in[4];
    const float* b1    = (const float*)d_in[5];
    const float* W2    = (const float*)d_in[6];
    const float* b2    = (const float*)d_in[7];
    const float* Wa    = (const float*)d_in[8];
    const float* Wb    = (const float*)d_in[9];

    float* ws = (float*)d_ws;
    float* A  = ws;                  // 131072 floats
    float* B  = ws + 131072;         // 131072 floats
    float* out = (float*)d_out;

    gate_ab_kernel<<<128, 256, 0, stream>>>(ctr, gamma, beta, W1, b1, W2, b2,
                                            Wa, Wb, A, B);
    fused_kernel<<<BS * SEQ / 16, 256, 0, stream>>>(x, A, B, out);
}

// Round 6
// 375.585 us; speedup vs baseline: 1.2335x; 1.2335x over previous
//
#include <hip/hip_runtime.h>
#include <math.h>

// Problem: bs=8, seq=2048, d_in=d_out=2048, R=8, ctr_out=32, ctr_final=4
// ws layout (floats): A[8*8*2048] | B[8*8*2048]  (B has SCALING folded in)

#define BS 8
#define SEQ 2048
#define DIM 2048
#define RR 8
#define SCALING 2.0f   // 16.0 / R

typedef float vf4 __attribute__((ext_vector_type(4)));

// ---------------------------------------------------------------------------
// Kernel 1: gating MLP + A/B generation. (unchanged — ~6 µs, off critical path)
// ---------------------------------------------------------------------------
__global__ void gate_ab_kernel(const float* __restrict__ ctr,
                               const float* __restrict__ gamma,
                               const float* __restrict__ beta,
                               const float* __restrict__ W1,
                               const float* __restrict__ b1,
                               const float* __restrict__ W2,
                               const float* __restrict__ b2,
                               const float* __restrict__ Wa,
                               const float* __restrict__ Wb,
                               float* __restrict__ A,
                               float* __restrict__ B) {
    __shared__ float z_s[BS][32];
    __shared__ float h_s[BS][60];
    __shared__ float logit_s[BS][4];
    __shared__ float gate_s[BS][4];
    const int tid = threadIdx.x;

    {
        const int b = tid >> 5, i = tid & 31;
        float v = ctr[b * 32 + i];
        float s = v;
        #pragma unroll
        for (int m = 16; m; m >>= 1) s += __shfl_xor(s, m, 64);
        const float mu = s * (1.0f / 32.0f);
        const float d = v - mu;
        float sq = d * d;
        #pragma unroll
        for (int m = 16; m; m >>= 1) sq += __shfl_xor(sq, m, 64);
        const float var = sq * (1.0f / 32.0f);
        z_s[b][i] = d * rsqrtf(var + 1e-5f) * gamma[i] + beta[i];
    }
    __syncthreads();

    for (int idx = tid; idx < BS * 60; idx += 256) {
        const int b = idx / 60, j = idx % 60;
        float acc = b1[j];
        #pragma unroll
        for (int k = 0; k < 32; ++k) acc += z_s[b][k] * W1[j * 32 + k];
        h_s[b][j] = fmaxf(acc, 0.0f);
    }
    __syncthreads();

    if (tid < 32) {
        const int b = tid >> 2, c = tid & 3;
        float acc = b2[c];
        for (int k = 0; k < 60; ++k) acc += h_s[b][k] * W2[c * 60 + k];
        logit_s[b][c] = acc;
    }
    __syncthreads();

    if (tid < 8) {
        float m = logit_s[tid][0];
        #pragma unroll
        for (int c = 1; c < 4; ++c) m = fmaxf(m, logit_s[tid][c]);
        float e[4], s = 0.0f;
        #pragma unroll
        for (int c = 0; c < 4; ++c) { e[c] = expf(logit_s[tid][c] - m); s += e[c]; }
        const float inv = 1.0f / s;
        #pragma unroll
        for (int c = 0; c < 4; ++c) gate_s[tid][c] = e[c] * inv;
    }
    __syncthreads();

    const vf4* __restrict__ Wa4 = (const vf4*)Wa;
    const vf4* __restrict__ Wb4 = (const vf4*)Wb;
    const int total = BS * RR * DIM;   // 131072
    for (int idx = blockIdx.x * 256 + tid; idx < total; idx += gridDim.x * 256) {
        const int b = idx >> 14, rd = idx & 16383;
        const vf4 g = *(const vf4*)gate_s[b];
        const vf4 wa = Wa4[rd];
        A[idx] = g.x * wa.x + g.y * wa.y + g.z * wa.z + g.w * wa.w;
        const vf4 wb = Wb4[rd];
        B[idx] = SCALING * (g.x * wb.x + g.y * wb.y + g.z * wb.z + g.w * wb.w);
    }
}

// ---------------------------------------------------------------------------
// Fused kernel v3.
// EVIDENCE LOG:
//  - v1 (LDS+barriers, float4 stores, only ds_read between stores):
//      WRITE 133 MB clean, 84 us.
//  - r1 (no-LDS, NT vf4 stores, B-loads interleaved with stores):
//      WRITE 556 MB, FETCH +148 MB (RMW), 293 us.
//  - r5 (same but PLAIN vf4 stores): byte-identical counters to r1.
//    => NT was irrelevant. Partial-line RMW comes from scalarized stores
//       whose components get separated by interleaved global loads, defeating
//       the TCC write-combiner.
// FIX: phase 2 has ZERO global loads between stores. Each wave owns a
// 512-col slice for all 16 tile rows; B-slice (16 float4) loaded into
// registers ONCE. xa crosses waves through a 512 B LDS buffer (one barrier).
// All vector memory ops use HIP float4 (v1-proven codegen).
// ---------------------------------------------------------------------------
__global__ void __launch_bounds__(256, 4)
fused_kernel(const float* __restrict__ x, const float* __restrict__ A,
             const float* __restrict__ B, float* __restrict__ out) {
    __shared__ float xa_lds[16 * RR];     // 512 B
    const int b    = blockIdx.x >> 7;     // 128 blocks per sample
    const int tile = blockIdx.x & 127;    // 16 rows per block
    const int wave = threadIdx.x >> 6, lane = threadIdx.x & 63;
    const int row0 = tile * 16;           // block's row base

    const float* __restrict__ xr =
        x + ((size_t)(b * SEQ + row0 + wave * 4)) * DIM;
    const float* __restrict__ Ab = A + b * (RR * DIM);

    float acc[4][8];
    #pragma unroll
    for (int i = 0; i < 4; ++i)
        #pragma unroll
        for (int r = 0; r < 8; ++r) acc[i][r] = 0.0f;

    // ---- phase 1: xa = x . A^T (4 rows/wave), x pipelined 1 deep ----
    float4 xcur[4], xnxt[4];
    {
        const int d0 = lane * 4;
        #pragma unroll
        for (int i = 0; i < 4; ++i)
            xcur[i] = *(const float4*)&xr[(size_t)i * DIM + d0];
    }
    #pragma unroll
    for (int j = 0; j < 8; ++j) {
        const int d = j * 256 + lane * 4;
        if (j < 7) {
            #pragma unroll
            for (int i = 0; i < 4; ++i)
                xnxt[i] = *(const float4*)&xr[(size_t)i * DIM + d + 256];
        }
        float4 a4[8];
        #pragma unroll
        for (int r = 0; r < 8; ++r) a4[r] = *(const float4*)&Ab[r * DIM + d];
        #pragma unroll
        for (int i = 0; i < 4; ++i) {
            #pragma unroll
            for (int r = 0; r < 8; ++r)
                acc[i][r] += xcur[i].x * a4[r].x + xcur[i].y * a4[r].y +
                             xcur[i].z * a4[r].z + xcur[i].w * a4[r].w;
        }
        #pragma unroll
        for (int i = 0; i < 4; ++i) xcur[i] = xnxt[i];
    }

    // butterfly reduce -> every lane holds its wave's 32 sums
    float xv[4][8];
    #pragma unroll
    for (int i = 0; i < 4; ++i) {
        #pragma unroll
        for (int r = 0; r < 8; ++r) {
            float v = acc[i][r];
            #pragma unroll
            for (int off = 32; off; off >>= 1) v += __shfl_xor(v, off, 64);
            xv[i][r] = v;
        }
    }

    // lanes 0..31 deposit xa into LDS: xa_lds[(wave*4+i)*8 + r], lane = i*8+r
    if (lane < 32) {
        float v = 0.0f;
        #pragma unroll
        for (int i = 0; i < 4; ++i)
            #pragma unroll
            for (int r = 0; r < 8; ++r)
                if (lane == i * 8 + r) v = xv[i][r];
        xa_lds[wave * 32 + lane] = v;
    }

    // ---- load this wave's B column-slice into registers (once) ----
    const int col0 = wave * 512 + lane * 4;
    const float* __restrict__ Bb = B + b * (RR * DIM);
    float4 b0[8], b1[8];
    #pragma unroll
    for (int r = 0; r < 8; ++r) {
        b0[r] = *(const float4*)&Bb[r * DIM + col0];
        b1[r] = *(const float4*)&Bb[r * DIM + col0 + 256];
    }

    __syncthreads();

    // ---- phase 2: out = xa . B — pure store burst, no global loads ----
    float* __restrict__ ob = out + ((size_t)(b * SEQ + row0)) * DIM + col0;
    #pragma unroll 4
    for (int i = 0; i < 16; ++i) {
        const float4 xlo = *(const float4*)&xa_lds[i * RR];
        const float4 xhi = *(const float4*)&xa_lds[i * RR + 4];
        float4 o0 = {0.0f, 0.0f, 0.0f, 0.0f};
        float4 o1 = {0.0f, 0.0f, 0.0f, 0.0f};
        o0.x += xlo.x * b0[0].x; o0.y += xlo.x * b0[0].y; o0.z += xlo.x * b0[0].z; o0.w += xlo.x * b0[0].w;
        o1.x += xlo.x * b1[0].x; o1.y += xlo.x * b1[0].y; o1.z += xlo.x * b1[0].z; o1.w += xlo.x * b1[0].w;
        o0.x += xlo.y * b0[1].x; o0.y += xlo.y * b0[1].y; o0.z += xlo.y * b0[1].z; o0.w += xlo.y * b0[1].w;
        o1.x += xlo.y * b1[1].x; o1.y += xlo.y * b1[1].y; o1.z += xlo.y * b1[1].z; o1.w += xlo.y * b1[1].w;
        o0.x += xlo.z * b0[2].x; o0.y += xlo.z * b0[2].y; o0.z += xlo.z * b0[2].z; o0.w += xlo.z * b0[2].w;
        o1.x += xlo.z * b1[2].x; o1.y += xlo.z * b1[2].y; o1.z += xlo.z * b1[2].z; o1.w += xlo.z * b1[2].w;
        o0.x += xlo.w * b0[3].x; o0.y += xlo.w * b0[3].y; o0.z += xlo.w * b0[3].z; o0.w += xlo.w * b0[3].w;
        o1.x += xlo.w * b1[3].x; o1.y += xlo.w * b1[3].y; o1.z += xlo.w * b1[3].z; o1.w += xlo.w * b1[3].w;
        o0.x += xhi.x * b0[4].x; o0.y += xhi.x * b0[4].y; o0.z += xhi.x * b0[4].z; o0.w += xhi.x * b0[4].w;
        o1.x += xhi.x * b1[4].x; o1.y += xhi.x * b1[4].y; o1.z += xhi.x * b1[4].z; o1.w += xhi.x * b1[4].w;
        o0.x += xhi.y * b0[5].x; o0.y += xhi.y * b0[5].y; o0.z += xhi.y * b0[5].z; o0.w += xhi.y * b0[5].w;
        o1.x += xhi.y * b1[5].x; o1.y += xhi.y * b1[5].y; o1.z += xhi.y * b1[5].z; o1.w += xhi.y * b1[5].w;
        o0.x += xhi.z * b0[6].x; o0.y += xhi.z * b0[6].y; o0.z += xhi.z * b0[6].z; o0.w += xhi.z * b0[6].w;
        o1.x += xhi.z * b1[6].x; o1.y += xhi.z * b1[6].y; o1.z += xhi.z * b1[6].z; o1.w += xhi.z * b1[6].w;
        o0.x += xhi.w * b0[7].x; o0.y += xhi.w * b0[7].y; o0.z += xhi.w * b0[7].z; o0.w += xhi.w * b0[7].w;
        o1.x += xhi.w * b1[7].x; o1.y += xhi.w * b1[7].y; o1.z += xhi.w * b1[7].z; o1.w += xhi.w * b1[7].w;
        *(float4*)&ob[(size_t)i * DIM] = o0;
        *(float4*)&ob[(size_t)i * DIM + 256] = o1;
    }
}

extern "C" void kernel_launch(void* const* d_in, const int* in_sizes, int n_in,
                              void* d_out, int out_size, void* d_ws, size_t ws_size,
                              hipStream_t stream) {
    const float* x     = (const float*)d_in[0];
    const float* ctr   = (const float*)d_in[1];
    const float* gamma = (const float*)d_in[2];
    const float* beta  = (const float*)d_in[3];
    const float* W1    = (const float*)d_in[4];
    const float* b1    = (const float*)d_in[5];
    const float* W2    = (const float*)d_in[6];
    const float* b2    = (const float*)d_in[7];
    const float* Wa    = (const float*)d_in[8];
    const float* Wb    = (const float*)d_in[9];

    float* ws = (float*)d_ws;
    float* A  = ws;                  // 131072 floats
    float* B  = ws + 131072;         // 131072 floats
    float* out = (float*)d_out;

    gate_ab_kernel<<<128, 256, 0, stream>>>(ctr, gamma, beta, W1, b1, W2, b2,
                                            Wa, Wb, A, B);
    fused_kernel<<<BS * SEQ / 16, 256, 0, stream>>>(x, A, B, out);
}